// Round 12
// baseline (156.017 us; speedup 1.0000x reference)
//
#include <hip/hip_runtime.h>
#include <math.h>

// Problem constants (fixed by setup_inputs): B=8, N=M=8192, D=3, fp32.
// MFMA chamfer: d^2 = wq + tw - 2 q.t per 32x32 tile via one
// v_mfma_f32_32x32x16_bf16 (fp32 split into bf16 hi/lo pairs along K, 13/16
// slots). One pass feeds BOTH min directions: row-mins in registers,
// col-mins via per-wave LDS slices (plain writes; merged once per block).
#define BB 8
#define NPTS 8192
#define NSIDE (BB * NPTS)     // 65536 points per side

#define BLOCK 256
#define WARPS 4               // waves per block; each wave owns 32 query rows
#define ROWSB (32 * WARPS)    // 128 rows per block
#define TCHUNK 2048           // targets per block
#define NTILES (TCHUNK / 32)  // 64 MFMA tiles per wave

#define INF_KEY 0x7F7F7F7F

typedef short bf16x8 __attribute__((ext_vector_type(8)));
typedef float f32x16 __attribute__((ext_vector_type(16)));

// Monotone float->int key so signed-int atomicMin orders like float.
__device__ __forceinline__ int enc_key(float v) {
    int b = __float_as_int(v);
    return b >= 0 ? b : (b ^ 0x7fffffff);
}
__device__ __forceinline__ float dec_key(int k) {
    int b = k >= 0 ? k : (k ^ 0x7fffffff);
    return __int_as_float(b);
}
__device__ __forceinline__ unsigned short f2bf(float f) {   // RNE fp32->bf16
    unsigned u = __float_as_uint(f);
    return (unsigned short)((u + 0x7FFFu + ((u >> 16) & 1u)) >> 16);
}
__device__ __forceinline__ float bfhi(float f, unsigned short* bits) {
    unsigned short h = f2bf(f);
    *bits = h;
    return __uint_as_float(((unsigned)h) << 16);
}
__device__ __forceinline__ void pack16(unsigned short* dst, const unsigned short* s) {
    uint4* d4 = (uint4*)dst;
    uint4 w0 = {(unsigned)s[0] | ((unsigned)s[1] << 16),
                (unsigned)s[2] | ((unsigned)s[3] << 16),
                (unsigned)s[4] | ((unsigned)s[5] << 16),
                (unsigned)s[6] | ((unsigned)s[7] << 16)};
    uint4 w1 = {(unsigned)s[8] | ((unsigned)s[9] << 16),
                (unsigned)s[10] | ((unsigned)s[11] << 16),
                (unsigned)s[12] | ((unsigned)s[13] << 16),
                (unsigned)s[14] | ((unsigned)s[15] << 16)};
    d4[0] = w0; d4[1] = w1;
}

// Slot pairing (A slot k multiplies B slot k): k0..2: x (h*h, h*l, l*h)
// k3..5: y  k6..8: z  k9,10: wq*1  k11,12: 1*tw  k13..15: 0.
__global__ __launch_bounds__(BLOCK) void chamfer_pack(
        const float* __restrict__ pred, const float* __restrict__ tgt,
        unsigned short* __restrict__ pA, unsigned short* __restrict__ pB,
        int* __restrict__ rk, int* __restrict__ ck, float* __restrict__ out) {
    int i = blockIdx.x * BLOCK + threadIdx.x;      // 0..NSIDE-1
    const unsigned short one = 0x3F80;             // bf16(1.0)
    {   // A-form from pred: a = -2*p, plus wq slots
        float x = pred[(size_t)i * 3 + 0], y = pred[(size_t)i * 3 + 1],
              z = pred[(size_t)i * 3 + 2];
        float wq = fmaf(x, x, fmaf(y, y, z * z));
        float ax = -2.0f * x, ay = -2.0f * y, az = -2.0f * z;
        unsigned short hx, hy, hz, hw;
        float fhx = bfhi(ax, &hx), fhy = bfhi(ay, &hy), fhz = bfhi(az, &hz);
        float fhw = bfhi(wq, &hw);
        unsigned short lx = f2bf(ax - fhx), ly = f2bf(ay - fhy),
                       lz = f2bf(az - fhz), lw = f2bf(wq - fhw);
        unsigned short s[16] = {hx, hx, lx, hy, hy, ly, hz, hz, lz,
                                hw, lw, one, one, 0, 0, 0};
        pack16(pA + (size_t)i * 16, s);
    }
    {   // B-form from tgt: b = t, plus tw slots
        float x = tgt[(size_t)i * 3 + 0], y = tgt[(size_t)i * 3 + 1],
              z = tgt[(size_t)i * 3 + 2];
        float tw = fmaf(x, x, fmaf(y, y, z * z));
        unsigned short hx, hy, hz, hw;
        float fhx = bfhi(x, &hx), fhy = bfhi(y, &hy), fhz = bfhi(z, &hz);
        float fhw = bfhi(tw, &hw);
        unsigned short lx = f2bf(x - fhx), ly = f2bf(y - fhy),
                       lz = f2bf(z - fhz), lw = f2bf(tw - fhw);
        unsigned short s[16] = {hx, lx, hx, hy, ly, hy, hz, lz, hz,
                                one, one, hw, lw, 0, 0, 0};
        pack16(pB + (size_t)i * 16, s);
    }
    rk[i] = INF_KEY;
    ck[i] = INF_KEY;
    if (i < BB) out[i] = 0.0f;
}

// grid = (NPTS/TCHUNK, NPTS/ROWSB, BB). A/B fragment: lane l supplies point
// (l&31), K-slots 8*(l>>5)+e. D layout (HW-verified): col = l&31,
// row = (k&3) + 8*(k>>2) + 4*(l>>5).
__global__ __launch_bounds__(BLOCK) void chamfer_mfma(
        const unsigned short* __restrict__ pA, const unsigned short* __restrict__ pB,
        int* __restrict__ rk, int* __restrict__ ck) {
    const int b = blockIdx.z;
    const int tb0 = blockIdx.x * TCHUNK;
    const int rb0 = blockIdx.y * ROWSB;
    const int wave = threadIdx.x >> 6;
    const int lane = threadIdx.x & 63;
    const int lp = lane & 31;            // point index within tile
    const int kh = lane >> 5;            // K half

    __shared__ float colslice[WARPS][TCHUNK];   // 32 KB, plain writes only

    const bf16x8* Ap = (const bf16x8*)pA;
    const bf16x8* Bp = (const bf16x8*)pB;
    const bf16x8 afrag = Ap[(size_t)(b * NPTS + rb0 + wave * 32 + lp) * 2 + kh];

    f32x16 zerov;
    #pragma unroll
    for (int k = 0; k < 16; ++k) zerov[k] = 0.0f;
    asm("" : "+v"(zerov));               // pin C operand to VGPRs

    float rmin[16];
    #pragma unroll
    for (int k = 0; k < 16; ++k) rmin[k] = INFINITY;

    const bf16x8* bp = Bp + (size_t)(b * NPTS + tb0 + lp) * 2 + kh;

    #pragma unroll 4
    for (int tile = 0; tile < NTILES; ++tile) {
        const bf16x8 bfrag = bp[tile * 64];     // 32 points * 2 halves
        f32x16 d = __builtin_amdgcn_mfma_f32_32x32x16_bf16(
            afrag, bfrag, zerov, 0, 0, 0);
        asm("" : "+v"(d));               // pin D to VGPRs (no accvgpr moves)
        // row side: per-lane partial mins (this lane's col only)
        #pragma unroll
        for (int k = 0; k < 16; ++k) rmin[k] = fminf(rmin[k], d[k]);
        // col side: min over the 16 rows this lane holds (min3-friendly)
        float c0 = fminf(fminf(d[0], d[1]), d[2]);
        float c1 = fminf(fminf(d[3], d[4]), d[5]);
        float c2 = fminf(fminf(d[6], d[7]), d[8]);
        float c3 = fminf(fminf(d[9], d[10]), d[11]);
        float c4 = fminf(fminf(d[12], d[13]), d[14]);
        float cp = fminf(fminf(fminf(c0, c1), fminf(c2, c3)),
                         fminf(c4, d[15]));
        cp = fminf(cp, __shfl_xor(cp, 32));     // merge the two K-halves
        if (lane < 32) colslice[wave][tile * 32 + lane] = cp;  // plain write
    }
    __syncthreads();

    // col merge: each slot written exactly once per wave slice
    for (int j = threadIdx.x; j < TCHUNK; j += BLOCK) {
        float m = fminf(fminf(colslice[0][j], colslice[1][j]),
                        fminf(colslice[2][j], colslice[3][j]));
        atomicMin(&ck[(size_t)b * NPTS + tb0 + j], enc_key(m));
    }

    // row reduce: butterfly across the 32 lanes sharing this kh
    #pragma unroll
    for (int k = 0; k < 16; ++k) {
        #pragma unroll
        for (int off = 1; off <= 16; off <<= 1)
            rmin[k] = fminf(rmin[k], __shfl_xor(rmin[k], off));
    }
    if (lp == 0) {
        #pragma unroll
        for (int k = 0; k < 16; ++k) {
            int row = (k & 3) + 8 * (k >> 2) + 4 * kh;
            atomicMin(&rk[(size_t)b * NPTS + rb0 + wave * 32 + row],
                      enc_key(rmin[k]));
        }
    }
}

// Keys hold d^2 mins. 32 slice-blocks per batch; atomicAdd into out[b].
#define FSLICE 32
__global__ __launch_bounds__(BLOCK) void chamfer_finalize(
        const int* __restrict__ rk, const int* __restrict__ ck,
        float* __restrict__ out) {
    const int b = blockIdx.x / FSLICE;
    const int s = blockIdx.x % FSLICE;
    const int t = threadIdx.x;
    const int i = b * NPTS + s * (NPTS / FSLICE) + t;
    float v = sqrtf(fmaxf(dec_key(rk[i]), 0.0f)) +
              sqrtf(fmaxf(dec_key(ck[i]), 0.0f));
    __shared__ float red[BLOCK];
    red[t] = v * (0.5f / (float)NPTS);
    __syncthreads();
    for (int off = BLOCK / 2; off > 0; off >>= 1) {
        if (t < off) red[t] += red[t + off];
        __syncthreads();
    }
    if (t == 0) atomicAdd(&out[b], red[0]);
}

extern "C" void kernel_launch(void* const* d_in, const int* in_sizes, int n_in,
                              void* d_out, int out_size, void* d_ws, size_t ws_size,
                              hipStream_t stream) {
    const float* pred = (const float*)d_in[0];
    const float* tgtp = (const float*)d_in[1];
    float* out = (float*)d_out;

    // ws: pA 2MB | pB 2MB | rk 256KB | ck 256KB
    char* ws = (char*)d_ws;
    unsigned short* pA = (unsigned short*)ws;
    unsigned short* pB = (unsigned short*)(ws + (size_t)NSIDE * 32);
    int* rk = (int*)(ws + (size_t)2 * NSIDE * 32);
    int* ck = rk + NSIDE;

    chamfer_pack<<<NSIDE / BLOCK, BLOCK, 0, stream>>>(pred, tgtp, pA, pB, rk, ck, out);

    // 4 t-chunks x 64 row-blocks x 8 batches = 2048 blocks (8 per CU).
    chamfer_mfma<<<dim3(NPTS / TCHUNK, NPTS / ROWSB, BB), BLOCK, 0, stream>>>(
        pA, pB, rk, ck);

    chamfer_finalize<<<BB * FSLICE, BLOCK, 0, stream>>>(rk, ck, out);
}